// Round 5
// baseline (613.864 us; speedup 1.0000x reference)
//
#include <hip/hip_runtime.h>
#include <hip/hip_bf16.h>

// ---------------------------------------------------------------------------
// FFT butterfly attention, single NORMAL dispatch (512 WGs x 512 thr, exactly
// 2 WGs/CU by resource math: 128 VGPR cap * 16 waves = full file, 2*69.6KB
// LDS <= 160KB) with a hand-rolled device-scope grid barrier:
//   prep (13 WGs): P_s = scale*Wq_s@Wk_s^T -> bf16 PT   | grid_barrier
//   phase1: stages 0..6  on contiguous 128-blocks (x2)  | grid_barrier
//   phase2: stages 7..12 on stride-128 gathers (x2, in place on out)
// Per stage: G = Xa@P (MFMA, A from LDS xb, B prefetched from global PT,
// double-buffered across stages), delta via split-wave dot + 5-step DPP
// reduce, w0 = sigmoid(delta), v mixed in registers (pair-local layout,
// one cross-lane exchange per stage: DPP / ds_swizzle / ds_bpermute).
// Barrier protocol = what cg::grid.sync emits: __syncthreads (drains vmcnt),
// tid0: release fence + device atomicAdd; last WG sets flag; spinners
// acquire-load flag, acquire fence, __syncthreads.
// ---------------------------------------------------------------------------

typedef __bf16 bf16x8 __attribute__((ext_vector_type(8)));
typedef float  f32x4  __attribute__((ext_vector_type(4)));

#define XSTR 136                    // bf16 elems per xb row (128 + 8 pad)
#define GSTR 132                    // f32 elems per gbuf row
#define XB_BYTES  (128 * XSTR * 2)  // 34816
#define GB_OFF    XB_BYTES
#define GB_BYTES  (64 * GSTR * 4)   // 33792
#define WT_OFF    (GB_OFF + GB_BYTES)
#define LDS_TOTAL (2 * XB_BYTES)    // 69632 = max(prep 69632, butterfly 68864)

#define NBLK 512
// d_ws layout: [0,256) barrier words; [256, 256+425984) PT
#define PT_OFF_BYTES 256

__device__ __forceinline__ float ubits(unsigned int u) {
    union { unsigned int u; float f; } v; v.u = u; return v.f;
}
__device__ __forceinline__ unsigned short f2bf(float f) {
    union { float f; unsigned int u; } v; v.f = f;
    unsigned int u = v.u;
    return (unsigned short)((u + 0x7fffu + ((u >> 16) & 1u)) >> 16);
}

#define DPP_MOV_F(x, ctrl) \
    __int_as_float(__builtin_amdgcn_update_dpp(0, __float_as_int(x), (ctrl), 0xF, 0xF, true))
#define DPP_ADD_F(s, ctrl) s += DPP_MOV_F(s, ctrl)

// cross-lane xor exchange with lane ^ (1<<u); u is compile-time-folded
__device__ __forceinline__ float xlane_u(float x, int u, int lane) {
    if (u == 0) return DPP_MOV_F(x, 0xB1);   // quad_perm xor1
    if (u == 1) return DPP_MOV_F(x, 0x4E);   // quad_perm xor2
    if (u == 2) return __int_as_float(__builtin_amdgcn_ds_swizzle(__float_as_int(x), 0x101F)); // xor4
    if (u == 3) return __int_as_float(__builtin_amdgcn_ds_swizzle(__float_as_int(x), 0x201F)); // xor8
    if (u == 4) return __int_as_float(__builtin_amdgcn_ds_swizzle(__float_as_int(x), 0x401F)); // xor16
    return __int_as_float(__builtin_amdgcn_ds_bpermute((lane ^ 32) << 2, __float_as_int(x))); // xor32
}

// ---- device-scope grid barrier (single-use cnt/flag pair per call) --------
__device__ __forceinline__ void grid_barrier(unsigned* cnt, unsigned* flag) {
    __syncthreads();                       // all WG mem ops drained (vmcnt 0)
    if (threadIdx.x == 0) {
        __threadfence();                   // agent release: L2 writeback
        unsigned v = __hip_atomic_fetch_add(cnt, 1u, __ATOMIC_ACQ_REL,
                                            __HIP_MEMORY_SCOPE_AGENT);
        if (v == NBLK - 1) {
            __hip_atomic_store(flag, 1u, __ATOMIC_RELEASE, __HIP_MEMORY_SCOPE_AGENT);
        } else {
            while (__hip_atomic_load(flag, __ATOMIC_ACQUIRE,
                                     __HIP_MEMORY_SCOPE_AGENT) == 0u)
                __builtin_amdgcn_s_sleep(8);
        }
        __threadfence();                   // agent acquire: invalidate caches
    }
    __syncthreads();
}

// ---------------- prep: PT[s][n][k] = scale * sum_e Wq[k][e] Wk[n][e] -------
__device__ __forceinline__ void prep_body(const float* __restrict__ qkw,
                                          unsigned short* __restrict__ PT,
                                          int s, char* smem) {
    unsigned short* wkb = (unsigned short*)smem;              // A: Wk rows (n)
    unsigned short* wqb = (unsigned short*)(smem + XB_BYTES); // B: Wq rows (k)
    const float* Wq = qkw + (size_t)s * 32768;
    const float* Wk = Wq + 16384;
    const int tid = threadIdx.x;
    const int rl = tid >> 5, c4 = tid & 31;
#pragma unroll
    for (int j = 0; j < 8; ++j) {
        int r = j * 16 + rl;
        float4 vq = ((const float4*)Wq)[r * 32 + c4];
        float4 vk = ((const float4*)Wk)[r * 32 + c4];
        ushort4 uq; uq.x = f2bf(vq.x); uq.y = f2bf(vq.y); uq.z = f2bf(vq.z); uq.w = f2bf(vq.w);
        ushort4 uk; uk.x = f2bf(vk.x); uk.y = f2bf(vk.y); uk.z = f2bf(vk.z); uk.w = f2bf(vk.w);
        *(ushort4*)(wqb + r * XSTR + c4 * 4) = uq;
        *(ushort4*)(wkb + r * XSTR + c4 * 4) = uk;
    }
    __syncthreads();
    const int lane = tid & 63, w = tid >> 6;
    const int lane15 = lane & 15, quad = lane >> 4;
    f32x4 acc[8] = {};
#pragma unroll
    for (int kk = 0; kk < 4; ++kk) {
        bf16x8 a = *(const bf16x8*)(wkb + (w * 16 + lane15) * XSTR + kk * 32 + quad * 8);
#pragma unroll
        for (int ct = 0; ct < 8; ++ct) {
            bf16x8 b = *(const bf16x8*)(wqb + (ct * 16 + lane15) * XSTR + kk * 32 + quad * 8);
            acc[ct] = __builtin_amdgcn_mfma_f32_16x16x32_bf16(a, b, acc[ct], 0, 0, 0);
        }
    }
    unsigned short* dst = PT + s * 16384;
#pragma unroll
    for (int ct = 0; ct < 8; ++ct)
#pragma unroll
        for (int r = 0; r < 4; ++r) {
            int n = w * 16 + quad * 4 + r;
            int k = ct * 16 + lane15;
            dst[n * 128 + k] = f2bf(acc[ct][r] * 0.17677669529663687f);
        }
}

// ---------------- fused butterfly stages ------------------------------------
template<int NS>
__device__ __forceinline__ void butterfly_body(const float* __restrict__ xsrc,
                                               const float* __restrict__ vsrc,
                                               float* __restrict__ vdst,
                                               const unsigned short* __restrict__ PT,
                                               int s0, int base, int h_off, int rstride,
                                               char* smem)
{
    unsigned short* xb   = (unsigned short*)smem;
    float*          gbuf = (float*)(smem + GB_OFF);
    float*          wt   = (float*)(smem + WT_OFF);

    const int tid = threadIdx.x;

    // ---- stage x -> xb (bf16), coalesced ----
    {
        const int rl = tid >> 5, c4 = tid & 31;
#pragma unroll
        for (int j = 0; j < 8; ++j) {
            int i  = j * 16 + rl;
            int gp = base + (i >> 6) * h_off + (i & 63) * rstride;
            float4 val = ((const float4*)xsrc)[gp * 32 + c4];
            ushort4 us; us.x = f2bf(val.x); us.y = f2bf(val.y);
            us.z = f2bf(val.z); us.w = f2bf(val.w);
            *(ushort4*)(xb + i * XSTR + c4 * 4) = us;
        }
    }

    const int lane = tid & 63, w = tid >> 6;
    const int lane15 = lane & 15, quad = lane >> 4;
    const int rg = w >> 2, cg = w & 3;

    // ---- v into registers, pair-local for stage 0: rows (2L, 2L+1) ----
    float vlo[16], vhi[16];
    {
        int r0 = 2 * lane, r1 = r0 + 1;
        int gp0 = base + (r0 >> 6) * h_off + (r0 & 63) * rstride;
        int gp1 = base + (r1 >> 6) * h_off + (r1 & 63) * rstride;
        const float* p0 = vsrc + (size_t)gp0 * 128 + w * 16;
        const float* p1 = vsrc + (size_t)gp1 * 128 + w * 16;
#pragma unroll
        for (int j = 0; j < 4; ++j) {
            float4 a = ((const float4*)p0)[j];
            float4 c = ((const float4*)p1)[j];
            vlo[4*j] = a.x; vlo[4*j+1] = a.y; vlo[4*j+2] = a.z; vlo[4*j+3] = a.w;
            vhi[4*j] = c.x; vhi[4*j+1] = c.y; vhi[4*j+2] = c.z; vhi[4*j+3] = c.w;
        }
    }

    // ---- PT B-fragment prefetch, double-buffered across stages ----
    uint4 bfr[2][8];
    {
        const unsigned short* PTs = PT + (size_t)s0 * 16384;
#pragma unroll
        for (int ct = 0; ct < 2; ++ct)
#pragma unroll
            for (int kk = 0; kk < 4; ++kk)
                bfr[0][ct * 4 + kk] = *(const uint4*)(PTs + (cg * 32 + ct * 16 + lane15) * 128 + kk * 32 + quad * 8);
    }
    __syncthreads();   // xb ready

#pragma unroll
    for (int u = 0; u < NS; ++u) {
        const int t   = 1 << u;
        const int tm1 = t - 1;
        const int cur = u & 1;

        // ---- GEMM: G[64x128] = Xa @ P (B from prefetched registers) ----
        {
            const int m0 = rg * 32 + lane15, m1 = m0 + 16;
            const int ar0 = ((m0 & ~tm1) << 1) | (m0 & tm1);
            const int ar1 = ((m1 & ~tm1) << 1) | (m1 & tm1);
            f32x4 acc[2][2] = {};
#pragma unroll
            for (int kk = 0; kk < 4; ++kk) {
                bf16x8 a0 = *(const bf16x8*)(xb + ar0 * XSTR + kk * 32 + quad * 8);
                bf16x8 a1 = *(const bf16x8*)(xb + ar1 * XSTR + kk * 32 + quad * 8);
#pragma unroll
                for (int ct = 0; ct < 2; ++ct) {
                    union { uint4 u; bf16x8 b; } cv; cv.u = bfr[cur][ct * 4 + kk];
                    acc[0][ct] = __builtin_amdgcn_mfma_f32_16x16x32_bf16(a0, cv.b, acc[0][ct], 0, 0, 0);
                    acc[1][ct] = __builtin_amdgcn_mfma_f32_16x16x32_bf16(a1, cv.b, acc[1][ct], 0, 0, 0);
                }
            }
            // prefetch next stage's B-fragments; drains under dot+mix
            if (u + 1 < NS) {
                const unsigned short* PTn = PT + (size_t)(s0 + u + 1) * 16384;
#pragma unroll
                for (int ct = 0; ct < 2; ++ct)
#pragma unroll
                    for (int kk = 0; kk < 4; ++kk)
                        bfr[cur ^ 1][ct * 4 + kk] = *(const uint4*)(PTn + (cg * 32 + ct * 16 + lane15) * 128 + kk * 32 + quad * 8);
            }
#pragma unroll
            for (int rt = 0; rt < 2; ++rt)
#pragma unroll
                for (int ct = 0; ct < 2; ++ct)
#pragma unroll
                    for (int r = 0; r < 4; ++r)
                        gbuf[(rg * 32 + rt * 16 + quad * 4 + r) * GSTR + cg * 32 + ct * 16 + lane15]
                            = acc[rt][ct][r];
        }
        __syncthreads();   // gbuf ready (also fences wt reads of prev stage)

        // ---- dot: 2 pairs per iter (32 lanes x 4 cols each) + DPP reduce ----
        {
            const int half = lane >> 5, l32 = lane & 31, c0 = l32 * 4;
#pragma unroll
            for (int it = 0; it < 4; ++it) {
                int p  = w * 8 + it * 2 + half;
                int ar = ((p & ~tm1) << 1) | (p & tm1);
                int br = ar + t;
                uint2 ua = *(const uint2*)(xb + ar * XSTR + c0);
                uint2 ub = *(const uint2*)(xb + br * XSTR + c0);
                float4 g = *(const float4*)(gbuf + p * GSTR + c0);
                float a0 = ubits(ua.x << 16), a1 = ubits(ua.x & 0xffff0000u);
                float a2 = ubits(ua.y << 16), a3 = ubits(ua.y & 0xffff0000u);
                float b0 = ubits(ub.x << 16), b1 = ubits(ub.x & 0xffff0000u);
                float b2 = ubits(ub.y << 16), b3 = ubits(ub.y & 0xffff0000u);
                float sm = g.x * (a0 - b0) + g.y * (a1 - b1)
                         + g.z * (a2 - b2) + g.w * (a3 - b3);
                DPP_ADD_F(sm, 0x111);  // row_shr:1
                DPP_ADD_F(sm, 0x112);  // row_shr:2
                DPP_ADD_F(sm, 0x114);  // row_shr:4
                DPP_ADD_F(sm, 0x118);  // row_shr:8
                DPP_ADD_F(sm, 0x142);  // row_bcast:15 -> lane31/63 hold sums
                if (l32 == 31) wt[p] = 1.0f / (1.0f + __expf(-sm));
            }
        }
        __syncthreads();   // weights ready

        // ---- mix (in-thread) + fused pair exchange for next stage ----
        {
            const float w0 = wt[lane];
            if (u < NS - 1) {
                const bool isE = ((lane >> u) & 1) == 0;
                const float wk = isE ? w0 : 1.0f - w0;
#pragma unroll
                for (int j = 0; j < 16; ++j) {
                    float a = vlo[j], c = vhi[j];
                    float s    = a + c;
                    float keep = c + wk * (a - c);   // E: out_a ; O: out_b
                    float send = s - keep;           // E: out_b ; O: out_a
                    float ex   = xlane_u(send, u, lane);
                    vlo[j] = isE ? keep : ex;
                    vhi[j] = isE ? ex : keep;
                }
            } else {
                const float w1 = 1.0f - w0;
#pragma unroll
                for (int j = 0; j < 16; ++j) {
                    float a = vlo[j], c = vhi[j];
                    float oa = w0 * a + w1 * c;
                    vlo[j] = oa;
                    vhi[j] = a + c - oa;
                }
            }
        }
    }

    // ---- store v registers -> vdst (layout of final stage NS-1) ----
    {
        const int FU = NS - 1;
        int r0 = ((lane >> FU) << (FU + 1)) | (lane & ((1 << FU) - 1));
        int r1 = r0 + (1 << FU);
        int gp0 = base + (r0 >> 6) * h_off + (r0 & 63) * rstride;
        int gp1 = base + (r1 >> 6) * h_off + (r1 & 63) * rstride;
        float* p0 = vdst + (size_t)gp0 * 128 + w * 16;
        float* p1 = vdst + (size_t)gp1 * 128 + w * 16;
#pragma unroll
        for (int j = 0; j < 4; ++j) {
            float4 a; a.x = vlo[4*j]; a.y = vlo[4*j+1]; a.z = vlo[4*j+2]; a.w = vlo[4*j+3];
            float4 c; c.x = vhi[4*j]; c.y = vhi[4*j+1]; c.z = vhi[4*j+2]; c.w = vhi[4*j+3];
            ((float4*)p0)[j] = a;
            ((float4*)p1)[j] = c;
        }
    }
}

// ---------------- the one fused kernel (normal launch + sw grid barrier) ----
__global__ __launch_bounds__(512, 4)
void fused_kernel(const float* __restrict__ x, const float* __restrict__ qkw,
                  float* __restrict__ out, unsigned char* __restrict__ ws)
{
    extern __shared__ char smem[];
    unsigned* bar = (unsigned*)ws;                       // cnt0@0 flag0@16 cnt1@32 flag1@48 (words)
    unsigned short* PT = (unsigned short*)(ws + PT_OFF_BYTES);

    // phase 0: prep (13 WGs compute P_s, others pass through)
    if (blockIdx.x < 13) prep_body(qkw, PT, blockIdx.x, smem);
    grid_barrier(bar + 0, bar + 16);

    // phase 1: stages 0..6 on contiguous 128-blocks; v init = x
    for (int rep = 0; rep < 2; ++rep) {
        int blk  = rep * NBLK + blockIdx.x;              // 0..1023
        int base = (blk >> 6) * 8192 + (blk & 63) * 128;
        butterfly_body<7>(x, x, out, PT, 0, base, /*h_off=*/64, /*rstride=*/1, smem);
    }
    grid_barrier(bar + 32, bar + 48);

    // phase 2: stages 7..12, stride-128 gathers, in place on out
    for (int rep = 0; rep < 2; ++rep) {
        int blk  = rep * NBLK + blockIdx.x;
        int base = (blk >> 6) * 8192 + (blk & 63) * 2;
        butterfly_body<6>(x, out, out, PT, 7, base, /*h_off=*/1, /*rstride=*/128, smem);
    }
}

extern "C" void kernel_launch(void* const* d_in, const int* in_sizes, int n_in,
                              void* d_out, int out_size, void* d_ws, size_t ws_size,
                              hipStream_t stream) {
    const float* x   = (const float*)d_in[0];
    const float* qkw = (const float*)d_in[1];
    float* out = (float*)d_out;
    unsigned char* ws = (unsigned char*)d_ws;  // [0,256) barrier, then PT (416 KB)

    (void)hipFuncSetAttribute((const void*)fused_kernel,
                              hipFuncAttributeMaxDynamicSharedMemorySize, LDS_TOTAL);

    // zero the barrier words (d_ws is poisoned 0xAA before every launch)
    (void)hipMemsetAsync(ws, 0, 256, stream);

    fused_kernel<<<NBLK, 512, LDS_TOTAL, stream>>>(x, qkw, out, ws);
}